// Round 1
// baseline (1559.208 us; speedup 1.0000x reference)
//
#include <hip/hip_runtime.h>

#define T_STEPS 1024
#define BATCH   64
#define NIN     32
#define NH      256
#define NOUT    16

typedef __attribute__((ext_vector_type(8))) _Float16 half8;
typedef __attribute__((ext_vector_type(4))) _Float16 half4;
typedef __attribute__((ext_vector_type(4))) float    f32x4;

__device__ __forceinline__ float fast_tanh(float x) {
  // tanh(x) = 1 - 2/(exp2(2*log2e*x)+1); exp2->inf/0 gives correct +-1 tails
  float e = __builtin_amdgcn_exp2f(x * 2.8853900817779268f);
  return 1.0f - 2.0f * __builtin_amdgcn_rcpf(e + 1.0f);
}

// Workgroup barrier that drains ONLY lgkmcnt (LDS), leaving global loads/stores
// in flight across the barrier (CK block_sync_lds pattern). __syncthreads()
// would emit s_waitcnt vmcnt(0) and serialize the q/u prefetch every step.
#define LDS_BARRIER() do {                                   \
    asm volatile("s_waitcnt lgkmcnt(0)" ::: "memory");       \
    __builtin_amdgcn_s_barrier();                            \
  } while (0)

// LDS layout: rlds[buf][m][n'] ushort, m in [0,16) batch, n in [0,288)
// (0..255 = r^T columns = k of next matmul, 256..287 = u^T). Row stride
// 288 ushort = 144 dwords; 8-element blocks XOR-swizzled by (m&3) so that
// b128 reads (B-frags) and b64 writes (C->A transform) are bank-optimal.
__global__ __launch_bounds__(256, 1)
void RecurrentNetwork_19628000543215_kernel(
    const float* __restrict__ inputs,  // [T][B][NIN]
    const float* __restrict__ noise,   // [T][B][NH]
    const float* __restrict__ x0,      // [B][NH]
    const float* __restrict__ Win,     // [NIN][NH]
    const float* __restrict__ Wrec,    // [NH][NH]
    const float* __restrict__ brec,    // [NH]
    const float* __restrict__ Wout,    // [NH][NOUT]
    const float* __restrict__ bout,    // [NOUT]
    float* __restrict__ out)           // outputs [T][B][NOUT] ++ states [T][B][NH]
{
  __shared__ alignas(16) unsigned short rlds[2 * 16 * 288];

  const int g   = blockIdx.x;       // batch group: batches [16g, 16g+16)
  const int tid = threadIdx.x;
  const int w   = tid >> 6;         // wave 0..3: owns n-columns [64w, 64w+64)
  const int l   = tid & 63;
  const int m   = l & 15;           // batch-in-group (MFMA C col / B col)
  const int q   = l >> 4;           // quad
  const int b   = 16 * g + m;       // global batch
  const int mx  = m & 3;            // LDS swizzle key

  float* outz = out;
  float* outx = out + (size_t)T_STEPS * BATCH * NOUT;

  // ---- weights -> persistent register A-fragments (W^T: A[n][k]) ----
  // A-frag layout (16x16x32): row = lane&15, k = (lane>>4)*8 + j.
  // k-index bijection only needs to MATCH between these gathers and the
  // r^T/u^T LDS layout (contraction is permutation-invariant).
  half8 wr[4][9];                   // kt 0..7 = Wrec^T, kt 8 = Win^T
  #pragma unroll
  for (int nt = 0; nt < 4; ++nt) {
    const int n = 64 * w + 16 * nt + m;
    #pragma unroll
    for (int kt = 0; kt < 9; ++kt) {
      #pragma unroll
      for (int j = 0; j < 8; ++j) {
        const int k = 32 * kt + 8 * q + j;
        const float v = (kt < 8) ? Wrec[(size_t)k * NH + n]
                                 : Win[(size_t)(k - 256) * NH + n];
        wr[nt][kt][j] = (_Float16)v;
      }
    }
  }
  half8 wo[8];                      // Wout^T A-frags (z-tile), row o = m-slot
  #pragma unroll
  for (int kt = 0; kt < 8; ++kt) {
    #pragma unroll
    for (int j = 0; j < 8; ++j) {
      const int k = 32 * kt + 8 * q + j;
      wo[kt][j] = (_Float16)Wout[(size_t)k * NOUT + m];
    }
  }

  f32x4 brec4[4], x[4];
  #pragma unroll
  for (int nt = 0; nt < 4; ++nt) {
    const int n0 = 64 * w + 16 * nt + 4 * q;
    brec4[nt] = *(const f32x4*)(brec + n0);
    x[nt]     = *(const f32x4*)(x0 + (size_t)b * NH + n0);
  }
  const f32x4 bout4 = *(const f32x4*)(bout + 4 * q);

  // ---- preloop: r_{-1}=tanh(x0) and u_0 into buf0; q_0 into regs ----
  #pragma unroll
  for (int nt = 0; nt < 4; ++nt) {
    const int n0 = 64 * w + 16 * nt + 4 * q;
    half4 r;
    r.x = (_Float16)fast_tanh(x[nt].x);
    r.y = (_Float16)fast_tanh(x[nt].y);
    r.z = (_Float16)fast_tanh(x[nt].z);
    r.w = (_Float16)fast_tanh(x[nt].w);
    const int blk = (n0 >> 3) ^ mx;
    *(half4*)&rlds[m * 288 + blk * 8 + (n0 & 7)] = r;
  }
  if (w == 1) {
    const float* up = inputs + (size_t)b * NIN + 8 * q;   // t = 0
    const f32x4 ua = *(const f32x4*)up;
    const f32x4 ub = *(const f32x4*)(up + 4);
    half8 uu;
    uu[0]=(_Float16)ua.x; uu[1]=(_Float16)ua.y; uu[2]=(_Float16)ua.z; uu[3]=(_Float16)ua.w;
    uu[4]=(_Float16)ub.x; uu[5]=(_Float16)ub.y; uu[6]=(_Float16)ub.z; uu[7]=(_Float16)ub.w;
    const int blk = (32 + q) ^ mx;
    *(half8*)&rlds[m * 288 + blk * 8] = uu;
  }
  f32x4 qv[4];
  #pragma unroll
  for (int nt = 0; nt < 4; ++nt) {
    const int n0 = 64 * w + 16 * nt + 4 * q;
    qv[nt] = *(const f32x4*)(noise + (size_t)b * NH + n0); // q_0
  }
  LDS_BARRIER();

  // ---- time loop: iter t reads buf[t&1] (r_{t-1}, u_t), writes buf[~] ----
  #pragma unroll 1
  for (int t = 0; t < T_STEPS; ++t) {
    const int rb = (t & 1) * 4608;
    const int wb = 4608 - rb;

    f32x4 ua, ub;                   // wave 1: issue u_{t+1} load early
    if (w == 1) {
      const int tu = (t + 1 < T_STEPS) ? t + 1 : T_STEPS - 1;
      const float* up = inputs + ((size_t)tu * BATCH + b) * NIN + 8 * q;
      ua = *(const f32x4*)up;
      ub = *(const f32x4*)(up + 4);
    }

    // acc = brec + r_{t-1}@Wrec + u_t@Win   (D rows = n, cols = batch)
    f32x4 acc[4];
    #pragma unroll
    for (int nt = 0; nt < 4; ++nt) acc[nt] = brec4[nt];
    f32x4 zac = bout4;              // z_{t-1} = bout + r_{t-1}@Wout

    #pragma unroll
    for (int kt = 0; kt < 9; ++kt) {
      const int blk = (4 * kt + q) ^ mx;
      const half8 bf = *(const half8*)&rlds[rb + m * 288 + blk * 8];
      #pragma unroll
      for (int nt = 0; nt < 4; ++nt)
        acc[nt] = __builtin_amdgcn_mfma_f32_16x16x32_f16(wr[nt][kt], bf, acc[nt], 0, 0, 0);
      if (kt < 8)
        zac = __builtin_amdgcn_mfma_f32_16x16x32_f16(wo[kt], bf, zac, 0, 0, 0);
    }

    // x_t = 0.9 x_{t-1} + 0.1 acc + q_t
    #pragma unroll
    for (int nt = 0; nt < 4; ++nt)
      x[nt] = 0.9f * x[nt] + 0.1f * acc[nt] + qv[nt];

    // states[t] store (fire-and-forget, no vmcnt drain at barrier)
    #pragma unroll
    for (int nt = 0; nt < 4; ++nt) {
      const int n0 = 64 * w + 16 * nt + 4 * q;
      *(f32x4*)(outx + ((size_t)t * BATCH + b) * NH + n0) = x[nt];
    }

    // prefetch q_{t+1}
    {
      const int tq = (t + 1 < T_STEPS) ? t + 1 : T_STEPS - 1;
      #pragma unroll
      for (int nt = 0; nt < 4; ++nt) {
        const int n0 = 64 * w + 16 * nt + 4 * q;
        qv[nt] = *(const f32x4*)(noise + ((size_t)tq * BATCH + b) * NH + n0);
      }
    }

    if (w == 0 && t > 0)            // store z_{t-1}
      *(f32x4*)(outz + ((size_t)(t - 1) * BATCH + b) * NOUT + 4 * q) = zac;

    // r_t = tanh(x_t) -> fp16 -> buf[next]  (C-layout -> B-operand layout)
    #pragma unroll
    for (int nt = 0; nt < 4; ++nt) {
      const int n0 = 64 * w + 16 * nt + 4 * q;
      half4 r;
      r.x = (_Float16)fast_tanh(x[nt].x);
      r.y = (_Float16)fast_tanh(x[nt].y);
      r.z = (_Float16)fast_tanh(x[nt].z);
      r.w = (_Float16)fast_tanh(x[nt].w);
      const int blk = (n0 >> 3) ^ mx;
      *(half4*)&rlds[wb + m * 288 + blk * 8 + (n0 & 7)] = r;
    }

    if (w == 1) {                   // stage u_{t+1} -> buf[next]
      half8 uu;
      uu[0]=(_Float16)ua.x; uu[1]=(_Float16)ua.y; uu[2]=(_Float16)ua.z; uu[3]=(_Float16)ua.w;
      uu[4]=(_Float16)ub.x; uu[5]=(_Float16)ub.y; uu[6]=(_Float16)ub.z; uu[7]=(_Float16)ub.w;
      const int blk = (32 + q) ^ mx;
      *(half8*)&rlds[wb + m * 288 + blk * 8] = uu;
    }

    LDS_BARRIER();
  }

  // ---- epilogue: z_{T-1} from r_{T-1} (sits in buf0 after t=1023) ----
  if (w == 0) {
    f32x4 zac = bout4;
    #pragma unroll
    for (int kt = 0; kt < 8; ++kt) {
      const int blk = (4 * kt + q) ^ mx;
      const half8 bf = *(const half8*)&rlds[m * 288 + blk * 8];
      zac = __builtin_amdgcn_mfma_f32_16x16x32_f16(wo[kt], bf, zac, 0, 0, 0);
    }
    *(f32x4*)(outz + ((size_t)(T_STEPS - 1) * BATCH + b) * NOUT + 4 * q) = zac;
  }
}

extern "C" void kernel_launch(void* const* d_in, const int* in_sizes, int n_in,
                              void* d_out, int out_size, void* d_ws, size_t ws_size,
                              hipStream_t stream) {
  (void)in_sizes; (void)n_in; (void)out_size; (void)d_ws; (void)ws_size;
  RecurrentNetwork_19628000543215_kernel<<<dim3(4), dim3(256), 0, stream>>>(
      (const float*)d_in[0],   // inputs
      (const float*)d_in[1],   // noise
      (const float*)d_in[2],   // x0
      (const float*)d_in[3],   // Win
      (const float*)d_in[4],   // Wrec
      (const float*)d_in[5],   // brec
      (const float*)d_in[6],   // Wout
      (const float*)d_in[7],   // bout
      (float*)d_out);
}

// Round 2
// 1400.115 us; speedup vs baseline: 1.1136x; 1.1136x over previous
//
#include <hip/hip_runtime.h>

#define T_STEPS 1024
#define BATCH   64
#define NIN     32
#define NH      256
#define NOUT    16

typedef __attribute__((ext_vector_type(8))) _Float16 half8;
typedef __attribute__((ext_vector_type(4))) _Float16 half4;
typedef __attribute__((ext_vector_type(4))) float    f32x4;

__device__ __forceinline__ float fast_tanh(float x) {
  // tanh(x) = 1 - 2/(exp2(2*log2e*x)+1); exp2->inf/0 gives correct +-1 tails
  float e = __builtin_amdgcn_exp2f(x * 2.8853900817779268f);
  return 1.0f - 2.0f * __builtin_amdgcn_rcpf(e + 1.0f);
}

// Drain ONLY lgkmcnt at the barrier: global stores/loads stay in flight
// (q/u prefetch + x/z stores must not serialize on vmcnt(0) each step).
#define LDS_BARRIER() do {                                   \
    asm volatile("s_waitcnt lgkmcnt(0)" ::: "memory");       \
    __builtin_amdgcn_s_barrier();                            \
  } while (0)

// LDS layout: rlds[buf][m][blk*8+j] ushort. Row m = batch-in-group, row
// stride 320 ushort (40 blocks of 8). Element n (0..255 = r, 256..287 = u)
// lives at blk = (n>>3) ^ (m&7), j = n&7. Key m&7 spreads all 8 bank-groups
// within each 16-lane phase (q is constant there) -> conflict-free b128
// reads. Row stride 40 blocks so (32+q)^(m&7) in [32,40) stays in-row.
#define ROW 320
#define BUFSZ (16 * ROW)

__global__ __launch_bounds__(512, 2)
void RecurrentNetwork_19628000543215_kernel(
    const float* __restrict__ inputs,  // [T][B][NIN]
    const float* __restrict__ noise,   // [T][B][NH]
    const float* __restrict__ x0,      // [B][NH]
    const float* __restrict__ Win,     // [NIN][NH]
    const float* __restrict__ Wrec,    // [NH][NH]
    const float* __restrict__ brec,    // [NH]
    const float* __restrict__ Wout,    // [NH][NOUT]
    const float* __restrict__ bout,    // [NOUT]
    float* __restrict__ out)           // outputs [T][B][NOUT] ++ states [T][B][NH]
{
  __shared__ alignas(16) unsigned short rlds[2 * BUFSZ];

  const int g   = blockIdx.x;       // batch group: batches [16g, 16g+16)
  const int tid = threadIdx.x;
  const int w   = tid >> 6;         // wave 0..7: owns n-columns [32w, 32w+32)
  const int l   = tid & 63;
  const int m   = l & 15;           // batch-in-group (B col / C col)
  const int q   = l >> 4;           // quad
  const int b   = 16 * g + m;       // global batch
  const int mx  = m & 7;            // LDS swizzle key

  float* outz = out;
  float* outx = out + (size_t)T_STEPS * BATCH * NOUT;

  // ---- weights -> persistent register A-frags, ALPHA pre-folded ----
  // A-frag (16x16x32): row = lane&15, k = (lane>>4)*8 + j. The lane->k map
  // only has to MATCH between this gather and the r/u LDS layout.
  half8 wr[2][9];                   // kt 0..7 = 0.1*Wrec^T, kt 8 = 0.1*Win^T
  #pragma unroll
  for (int nt = 0; nt < 2; ++nt) {
    const int n = 32 * w + 16 * nt + m;
    #pragma unroll
    for (int kt = 0; kt < 9; ++kt) {
      #pragma unroll
      for (int j = 0; j < 8; ++j) {
        const int k = 32 * kt + 8 * q + j;
        const float v = (kt < 8) ? Wrec[(size_t)k * NH + n]
                                 : Win[(size_t)(k - 256) * NH + n];
        wr[nt][kt][j] = (_Float16)(0.1f * v);
      }
    }
  }
  half8 wo[8];                      // Wout^T A-frags (z-tile), UNSCALED
  if (w == 0) {
    #pragma unroll
    for (int kt = 0; kt < 8; ++kt)
      #pragma unroll
      for (int j = 0; j < 8; ++j)
        wo[kt][j] = (_Float16)Wout[(size_t)(32 * kt + 8 * q + j) * NOUT + m];
  }

  f32x4 brecs[2], x[2];
  #pragma unroll
  for (int nt = 0; nt < 2; ++nt) {
    const int n0 = 32 * w + 16 * nt + 4 * q;
    const f32x4 br = *(const f32x4*)(brec + n0);
    brecs[nt] = 0.1f * br;          // folded alpha
    x[nt]     = *(const f32x4*)(x0 + (size_t)b * NH + n0);
  }
  const f32x4 bout4 = *(const f32x4*)(bout + 4 * q);

  // ---- preloop: r_{-1}=tanh(x0), u_0 -> buf0; q_0 -> regs ----
  #pragma unroll
  for (int nt = 0; nt < 2; ++nt) {
    const int n0 = 32 * w + 16 * nt + 4 * q;
    half4 r;
    r.x = (_Float16)fast_tanh(x[nt].x);
    r.y = (_Float16)fast_tanh(x[nt].y);
    r.z = (_Float16)fast_tanh(x[nt].z);
    r.w = (_Float16)fast_tanh(x[nt].w);
    const int blk = (n0 >> 3) ^ mx;
    *(half4*)&rlds[m * ROW + blk * 8 + (n0 & 7)] = r;
  }
  if (w == 1) {
    const float* up = inputs + (size_t)b * NIN + 8 * q;   // t = 0
    const f32x4 ua = *(const f32x4*)up;
    const f32x4 ub = *(const f32x4*)(up + 4);
    half8 uu;
    uu[0]=(_Float16)ua.x; uu[1]=(_Float16)ua.y; uu[2]=(_Float16)ua.z; uu[3]=(_Float16)ua.w;
    uu[4]=(_Float16)ub.x; uu[5]=(_Float16)ub.y; uu[6]=(_Float16)ub.z; uu[7]=(_Float16)ub.w;
    const int blk = (32 + q) ^ mx;
    *(half8*)&rlds[m * ROW + blk * 8] = uu;
  }
  f32x4 qv[2];
  #pragma unroll
  for (int nt = 0; nt < 2; ++nt) {
    const int n0 = 32 * w + 16 * nt + 4 * q;
    qv[nt] = *(const f32x4*)(noise + (size_t)b * NH + n0); // q_0
  }
  LDS_BARRIER();

  // ---- time loop: iter t reads buf[t&1] (r_{t-1}, u_t), writes the other ----
  #pragma unroll 1
  for (int t = 0; t < T_STEPS; ++t) {
    const int rb = (t & 1) * BUFSZ;
    const int wb = BUFSZ - rb;
    const int tn = (t + 1 < T_STEPS) ? t + 1 : T_STEPS - 1;

    f32x4 ua, ub;                   // wave 1: u_{t+1} load issued early
    if (w == 1) {
      const float* up = inputs + ((size_t)tn * BATCH + b) * NIN + 8 * q;
      ua = *(const f32x4*)up;
      ub = *(const f32x4*)(up + 4);
    }
    f32x4 qn0 = *(const f32x4*)(noise + ((size_t)tn * BATCH + b) * NH + 32 * w + 4 * q);
    f32x4 qn1 = *(const f32x4*)(noise + ((size_t)tn * BATCH + b) * NH + 32 * w + 16 + 4 * q);

    // acc = q_t + 0.1*brec + r_{t-1}@(0.1*Wrec) + u_t@(0.1*Win)
    f32x4 acc[2];
    #pragma unroll
    for (int nt = 0; nt < 2; ++nt) acc[nt] = brecs[nt] + qv[nt];
    f32x4 zac = bout4;              // z_{t-1} = bout + r_{t-1}@Wout (wave 0)

    #pragma unroll
    for (int kt = 0; kt < 9; ++kt) {
      const int blk = (4 * kt + q) ^ mx;
      const half8 bf = *(const half8*)&rlds[rb + m * ROW + blk * 8];
      #pragma unroll
      for (int nt = 0; nt < 2; ++nt)
        acc[nt] = __builtin_amdgcn_mfma_f32_16x16x32_f16(wr[nt][kt], bf, acc[nt], 0, 0, 0);
      if (w == 0 && kt < 8)
        zac = __builtin_amdgcn_mfma_f32_16x16x32_f16(wo[kt], bf, zac, 0, 0, 0);
    }

    // x_t = 0.9*x_{t-1} + acc ; store states[t]; stage r_t, u_{t+1}
    #pragma unroll
    for (int nt = 0; nt < 2; ++nt) {
      x[nt] = 0.9f * x[nt] + acc[nt];
      const int n0 = 32 * w + 16 * nt + 4 * q;
      *(f32x4*)(outx + ((size_t)t * BATCH + b) * NH + n0) = x[nt];
    }

    if (w == 0 && t > 0)            // store z_{t-1}
      *(f32x4*)(outz + ((size_t)(t - 1) * BATCH + b) * NOUT + 4 * q) = zac;

    #pragma unroll
    for (int nt = 0; nt < 2; ++nt) {
      const int n0 = 32 * w + 16 * nt + 4 * q;
      half4 r;
      r.x = (_Float16)fast_tanh(x[nt].x);
      r.y = (_Float16)fast_tanh(x[nt].y);
      r.z = (_Float16)fast_tanh(x[nt].z);
      r.w = (_Float16)fast_tanh(x[nt].w);
      const int blk = (n0 >> 3) ^ mx;
      *(half4*)&rlds[wb + m * ROW + blk * 8 + (n0 & 7)] = r;
    }

    if (w == 1) {                   // stage u_{t+1}
      half8 uu;
      uu[0]=(_Float16)ua.x; uu[1]=(_Float16)ua.y; uu[2]=(_Float16)ua.z; uu[3]=(_Float16)ua.w;
      uu[4]=(_Float16)ub.x; uu[5]=(_Float16)ub.y; uu[6]=(_Float16)ub.z; uu[7]=(_Float16)ub.w;
      const int blk = (32 + q) ^ mx;
      *(half8*)&rlds[wb + m * ROW + blk * 8] = uu;
    }

    qv[0] = qn0;                    // q_{t+1} now owned
    qv[1] = qn1;

    LDS_BARRIER();
  }

  // ---- epilogue: z_{T-1} from r_{T-1} (in buf0 after t=1023) ----
  if (w == 0) {
    f32x4 zac = bout4;
    #pragma unroll
    for (int kt = 0; kt < 8; ++kt) {
      const int blk = (4 * kt + q) ^ mx;
      const half8 bf = *(const half8*)&rlds[m * ROW + blk * 8];
      zac = __builtin_amdgcn_mfma_f32_16x16x32_f16(wo[kt], bf, zac, 0, 0, 0);
    }
    *(f32x4*)(outz + ((size_t)(T_STEPS - 1) * BATCH + b) * NOUT + 4 * q) = zac;
  }
}

extern "C" void kernel_launch(void* const* d_in, const int* in_sizes, int n_in,
                              void* d_out, int out_size, void* d_ws, size_t ws_size,
                              hipStream_t stream) {
  (void)in_sizes; (void)n_in; (void)out_size; (void)d_ws; (void)ws_size;
  RecurrentNetwork_19628000543215_kernel<<<dim3(4), dim3(512), 0, stream>>>(
      (const float*)d_in[0],   // inputs
      (const float*)d_in[1],   // noise
      (const float*)d_in[2],   // x0
      (const float*)d_in[3],   // Win
      (const float*)d_in[4],   // Wrec
      (const float*)d_in[5],   // brec
      (const float*)d_in[6],   // Wout
      (const float*)d_in[7],   // bout
      (float*)d_out);
}